// Round 1
// baseline (2415.721 us; speedup 1.0000x reference)
//
#include <hip/hip_runtime.h>

#define NH 12
#define HD 32
#define DIMC 384
#define BATCH 32
#define HWIMG 56
#define HW 3136          // 56*56
#define QKV_M 1152       // 3*DIM

// ---------------- Tiled fp32 GEMM: C[b][m][hw] = sum_k A[m][k] * X[b][k][hw] (+bias[m]) ----------
// A: [M,K] row-major weight; X: [B,K,HW]; C: [B,M,HW]
template<bool ADD_BIAS>
__global__ __launch_bounds__(256) void gemm_nchw(
    const float* __restrict__ A,
    const float* __restrict__ X,
    const float* __restrict__ bias,
    float* __restrict__ C,
    int M, int K)
{
    constexpr int BM = 64, BN = 64, BK = 16;
    const int b = blockIdx.z;
    const float* Xb = X + (size_t)b * K * HW;
    float* Cb = C + (size_t)b * M * HW;
    const int m0 = blockIdx.y * BM;
    const int n0 = blockIdx.x * BN;

    __shared__ float As[BK][BM];   // transposed: As[k][m]
    __shared__ float Bs[BK][BN];

    const int tid = threadIdx.x;
    // A tile: 64 rows x 16 k, each thread loads one float4 along k
    const int arow = tid / 4;          // 0..63
    const int acol = (tid % 4) * 4;    // 0,4,8,12
    // B tile: 16 k x 64 n, each thread loads one float4 along n
    const int brow = tid / 16;         // 0..15
    const int bcol = (tid % 16) * 4;   // 0..60

    const int mt = (tid / 16) * 4;     // output rows
    const int nt = (tid % 16) * 4;     // output cols

    float acc[4][4] = {{0.f}};

    for (int k0 = 0; k0 < K; k0 += BK) {
        float4 av = *reinterpret_cast<const float4*>(&A[(size_t)(m0 + arow) * K + k0 + acol]);
        As[acol + 0][arow] = av.x;
        As[acol + 1][arow] = av.y;
        As[acol + 2][arow] = av.z;
        As[acol + 3][arow] = av.w;
        float4 bv = *reinterpret_cast<const float4*>(&Xb[(size_t)(k0 + brow) * HW + n0 + bcol]);
        *reinterpret_cast<float4*>(&Bs[brow][bcol]) = bv;
        __syncthreads();
        #pragma unroll
        for (int k = 0; k < BK; ++k) {
            float a0 = As[k][mt + 0], a1 = As[k][mt + 1], a2 = As[k][mt + 2], a3 = As[k][mt + 3];
            float b0 = Bs[k][nt + 0], b1 = Bs[k][nt + 1], b2 = Bs[k][nt + 2], b3 = Bs[k][nt + 3];
            acc[0][0] += a0 * b0; acc[0][1] += a0 * b1; acc[0][2] += a0 * b2; acc[0][3] += a0 * b3;
            acc[1][0] += a1 * b0; acc[1][1] += a1 * b1; acc[1][2] += a1 * b2; acc[1][3] += a1 * b3;
            acc[2][0] += a2 * b0; acc[2][1] += a2 * b1; acc[2][2] += a2 * b2; acc[2][3] += a2 * b3;
            acc[3][0] += a3 * b0; acc[3][1] += a3 * b1; acc[3][2] += a3 * b2; acc[3][3] += a3 * b3;
        }
        __syncthreads();
    }

    #pragma unroll
    for (int i = 0; i < 4; ++i) {
        float bi = ADD_BIAS ? bias[m0 + mt + i] : 0.f;
        float4 r;
        r.x = acc[i][0] + bi; r.y = acc[i][1] + bi; r.z = acc[i][2] + bi; r.w = acc[i][3] + bi;
        *reinterpret_cast<float4*>(&Cb[(size_t)(m0 + mt + i) * HW + n0 + nt]) = r;
    }
}

// ---------------- Windowed attention: one block per (window, head) ----------------
// qkv: [B, 1152, HW] with channel o = which*384 + head*32 + d
// out: [B, 384, HW]  (c = head*32 + d)
__global__ __launch_bounds__(256) void win_attn(
    const float* __restrict__ qkv,
    const float* __restrict__ bias_table,  // [169, 12]
    const int* __restrict__ rel_index,     // [49*49]
    float* __restrict__ out)
{
    const int bid = blockIdx.x;
    const int head = bid % NH;
    const int win = bid / NH;
    const int ww = win % 8;
    const int hh = (win / 8) % 8;
    const int b = win / 64;

    __shared__ float q[49][33], k[49][33], v[49][33];
    __shared__ float dots[49][50];

    const int tid = threadIdx.x;
    const size_t base_q = ((size_t)b * QKV_M + head * HD) * HW;
    const size_t base_k = base_q + (size_t)DIMC * HW;
    const size_t base_v = base_q + (size_t)(2 * DIMC) * HW;
    const int spatial0 = (hh * 7) * HWIMG + ww * 7;

    for (int idx = tid; idx < 49 * 32; idx += 256) {
        int d = idx / 49;
        int i = idx % 49;
        int off = spatial0 + (i / 7) * HWIMG + (i % 7);
        q[i][d] = qkv[base_q + (size_t)d * HW + off];
        k[i][d] = qkv[base_k + (size_t)d * HW + off];
        v[i][d] = qkv[base_v + (size_t)d * HW + off];
    }
    __syncthreads();

    const float scale = 0.17677669529663687f;  // 32^-0.5
    for (int idx = tid; idx < 49 * 49; idx += 256) {
        int i = idx / 49, j = idx % 49;
        float s = 0.f;
        #pragma unroll
        for (int d = 0; d < HD; ++d) s += q[i][d] * k[j][d];
        dots[i][j] = s * scale + bias_table[rel_index[idx] * NH + head];
    }
    __syncthreads();

    if (tid < 49) {
        float m = -1e30f;
        for (int j = 0; j < 49; ++j) m = fmaxf(m, dots[tid][j]);
        float sum = 0.f;
        for (int j = 0; j < 49; ++j) { float e = __expf(dots[tid][j] - m); dots[tid][j] = e; sum += e; }
        float inv = 1.f / sum;
        for (int j = 0; j < 49; ++j) dots[tid][j] *= inv;
    }
    __syncthreads();

    for (int idx = tid; idx < 49 * 32; idx += 256) {
        int d = idx / 49;
        int i = idx % 49;
        float s = 0.f;
        #pragma unroll
        for (int j = 0; j < 49; ++j) s += dots[i][j] * v[j][d];
        int off = spatial0 + (i / 7) * HWIMG + (i % 7);
        out[((size_t)b * DIMC + head * HD + d) * HW + off] = s;
    }
}

extern "C" void kernel_launch(void* const* d_in, const int* in_sizes, int n_in,
                              void* d_out, int out_size, void* d_ws, size_t ws_size,
                              hipStream_t stream) {
    const float* x          = (const float*)d_in[0];  // [32, 384, 56, 56]
    const float* w_qkv      = (const float*)d_in[1];  // [1152, 384]
    const float* w_proj     = (const float*)d_in[2];  // [384, 384]
    const float* b_proj     = (const float*)d_in[3];  // [384]
    const float* bias_table = (const float*)d_in[4];  // [169, 12]
    const int*   rel_index  = (const int*)d_in[5];    // [49, 49]

    float* out = (float*)d_out;

    float* qkv      = (float*)d_ws;                              // [32, 1152, 3136] fp32
    float* attn_out = qkv + (size_t)BATCH * QKV_M * HW;          // [32, 384, 3136] fp32

    // GEMM1: qkv = w_qkv @ x   (per batch)
    gemm_nchw<false><<<dim3(HW / 64, QKV_M / 64, BATCH), 256, 0, stream>>>(
        w_qkv, x, nullptr, qkv, QKV_M, DIMC);

    // Attention per (window, head)
    win_attn<<<dim3(BATCH * 64 * NH), 256, 0, stream>>>(qkv, bias_table, rel_index, attn_out);

    // GEMM2: out = w_proj @ attn_out + b_proj
    gemm_nchw<true><<<dim3(HW / 64, DIMC / 64, BATCH), 256, 0, stream>>>(
        w_proj, attn_out, b_proj, out, DIMC, DIMC);
}

// Round 2
// 717.852 us; speedup vs baseline: 3.3652x; 3.3652x over previous
//
#include <hip/hip_runtime.h>

#define NH 12
#define HD 32
#define DIMC 384
#define BATCH 32
#define HWIMG 56
#define HW 3136          // 56*56
#define NPAD 3200        // HW padded to multiple of 128
#define NTOT (BATCH * NPAD)  // 102400 rows total
#define QKV_M 1152       // 3*DIM
#define KDIM 384

typedef __attribute__((ext_vector_type(8))) short short8;
typedef __attribute__((ext_vector_type(4))) short short4v;
typedef __attribute__((ext_vector_type(4))) float f32x4;

typedef const __attribute__((address_space(1))) unsigned int* gas_ptr;
typedef __attribute__((address_space(3))) unsigned int* las_ptr;

__device__ __forceinline__ unsigned short f2bf(float f) {
    union { float f; unsigned u; } v; v.f = f;
    unsigned r = v.u + 0x7FFF + ((v.u >> 16) & 1);
    return (unsigned short)(r >> 16);
}
__device__ __forceinline__ float bf2f(unsigned short h) {
    union { unsigned u; float f; } v; v.u = ((unsigned)h) << 16;
    return v.f;
}

// ---------------- fp32 -> bf16 weight convert ----------------
__global__ __launch_bounds__(256) void cvt_w(const float* __restrict__ in,
                                             unsigned short* __restrict__ out, int n) {
    int i = blockIdx.x * 256 + threadIdx.x;
    if (i < n) out[i] = f2bf(in[i]);
}

// ---------------- x [B,384,HW] fp32 -> xt [B*NPAD, 384] bf16 (transpose) ----------------
__global__ __launch_bounds__(256) void cvt_x(const float* __restrict__ x,
                                             unsigned short* __restrict__ xt) {
    __shared__ float tile[32][33];
    const int b = blockIdx.z, c0 = blockIdx.y * 32, n0 = blockIdx.x * 32;
    const int tid = threadIdx.x;
    const int cl = tid >> 5, nl = tid & 31;
    #pragma unroll
    for (int p = 0; p < 4; ++p)
        tile[cl + p * 8][nl] = x[((size_t)b * DIMC + c0 + cl + p * 8) * HW + n0 + nl];
    __syncthreads();
    const int nl2 = tid >> 5, cl2 = tid & 31;
    #pragma unroll
    for (int p = 0; p < 4; ++p)
        xt[((size_t)b * NPAD + n0 + nl2 + p * 8) * KDIM + c0 + cl2] = f2bf(tile[cl2][nl2 + p * 8]);
}

// ---------------- bf16 MFMA GEMM ----------------
// C[m, ng] = sum_k A[m,k] * Bm[ng,k]   (A: [M,384] bf16 row-major; Bm: [NTOT,384] bf16)
// MODE 0: store C^T as bf16: Cout[ng * ldc + m]           (for qkv / attention input)
// MODE 1: store fp32 NCHW + bias: Cout[(b*384+m)*HW + n]  (final output)
template<int MODE>
__global__ __launch_bounds__(256) void gemm_mfma(
    const unsigned short* __restrict__ A,
    const unsigned short* __restrict__ Bm,
    const float* __restrict__ bias,
    void* __restrict__ Cout,
    int ldc)
{
    __shared__ char Al[128 * 128];   // 128 rows x 64 bf16 (128B), XOR-swizzled 16B slots
    __shared__ char Bl[128 * 128];
    const int tid = threadIdx.x;
    const int m0 = blockIdx.y * 128;
    const int ng0 = blockIdx.x * 128;

    const int lane = tid & 63;
    const int wv = tid >> 6;
    const int wr = wv >> 1, wc = wv & 1;   // 2x2 wave grid, 64x64 per wave
    const int lrow = lane & 15, kgrp = lane >> 4;

    f32x4 acc[4][4] = {};

    const char* Abase = (const char*)(A + (size_t)m0 * KDIM);
    const char* Bbase = (const char*)(Bm + (size_t)ng0 * KDIM);

    for (int kt = 0; kt < KDIM / 64; ++kt) {
        const int kb = kt * 128;  // byte offset within a 768B source row
        #pragma unroll
        for (int it = 0; it < 4; ++it) {
            int chunk = it * 256 + tid;
            int row = chunk >> 3, slot = chunk & 7;
            int scol = (slot ^ (row & 7)) * 16;   // inverse-swizzled SOURCE, linear LDS dest
            __builtin_amdgcn_global_load_lds(
                (gas_ptr)(Abase + (size_t)row * (KDIM * 2) + kb + scol),
                (las_ptr)(Al + chunk * 16), 16, 0, 0);
        }
        #pragma unroll
        for (int it = 0; it < 4; ++it) {
            int chunk = it * 256 + tid;
            int row = chunk >> 3, slot = chunk & 7;
            int scol = (slot ^ (row & 7)) * 16;
            __builtin_amdgcn_global_load_lds(
                (gas_ptr)(Bbase + (size_t)row * (KDIM * 2) + kb + scol),
                (las_ptr)(Bl + chunk * 16), 16, 0, 0);
        }
        __syncthreads();
        #pragma unroll
        for (int kk = 0; kk < 2; ++kk) {
            short8 af[4], bfr[4];
            #pragma unroll
            for (int i = 0; i < 4; ++i) {
                int row = wr * 64 + i * 16 + lrow;
                int slot = (kk * 4 + kgrp) ^ (row & 7);   // swizzled read (same involution)
                af[i] = *(const short8*)(Al + row * 128 + slot * 16);
            }
            #pragma unroll
            for (int j = 0; j < 4; ++j) {
                int row = wc * 64 + j * 16 + lrow;
                int slot = (kk * 4 + kgrp) ^ (row & 7);
                bfr[j] = *(const short8*)(Bl + row * 128 + slot * 16);
            }
            #pragma unroll
            for (int i = 0; i < 4; ++i)
                #pragma unroll
                for (int j = 0; j < 4; ++j)
                    acc[i][j] = __builtin_amdgcn_mfma_f32_16x16x32_bf16(af[i], bfr[j], acc[i][j], 0, 0, 0);
        }
        __syncthreads();
    }

    // Epilogue. C fragment: col(n) = lane&15, row(m) = kgrp*4 + reg.
    if (MODE == 0) {
        unsigned short* C = (unsigned short*)Cout;
        #pragma unroll
        for (int i = 0; i < 4; ++i) {
            int m = m0 + wr * 64 + i * 16 + kgrp * 4;
            #pragma unroll
            for (int j = 0; j < 4; ++j) {
                int ng = ng0 + wc * 64 + j * 16 + lrow;
                short4v pk;
                pk.x = (short)f2bf(acc[i][j].x);
                pk.y = (short)f2bf(acc[i][j].y);
                pk.z = (short)f2bf(acc[i][j].z);
                pk.w = (short)f2bf(acc[i][j].w);
                *(short4v*)(C + (size_t)ng * ldc + m) = pk;
            }
        }
    } else {
        float* C = (float*)Cout;
        #pragma unroll
        for (int i = 0; i < 4; ++i) {
            int m = m0 + wr * 64 + i * 16 + kgrp * 4;
            float b0 = bias[m + 0], b1 = bias[m + 1], b2 = bias[m + 2], b3 = bias[m + 3];
            #pragma unroll
            for (int j = 0; j < 4; ++j) {
                int ng = ng0 + wc * 64 + j * 16 + lrow;
                int bb = ng / NPAD;
                int n = ng % NPAD;
                if (n < HW) {
                    C[((size_t)bb * DIMC + m + 0) * HW + n] = acc[i][j].x + b0;
                    C[((size_t)bb * DIMC + m + 1) * HW + n] = acc[i][j].y + b1;
                    C[((size_t)bb * DIMC + m + 2) * HW + n] = acc[i][j].z + b2;
                    C[((size_t)bb * DIMC + m + 3) * HW + n] = acc[i][j].w + b3;
                }
            }
        }
    }
}

// ---------------- Windowed attention (fp32 compute, bf16 I/O, n-major layout) -------------
// qkv: [NTOT, 1152] bf16, channel = which*384 + head*32 + d
// out: [NTOT, 384] bf16
__global__ __launch_bounds__(256) void win_attn(
    const unsigned short* __restrict__ qkv,
    const float* __restrict__ bias_table,  // [169, 12]
    const int* __restrict__ rel_index,     // [49*49]
    unsigned short* __restrict__ outb)
{
    const int bid = blockIdx.x;
    const int head = bid % NH;
    const int win = bid / NH;
    const int ww = win % 8;
    const int hh = (win / 8) % 8;
    const int b = win / 64;

    __shared__ float q[49][33], k[49][33], v[49][33];
    __shared__ float dots[49][50];

    const int tid = threadIdx.x;
    const int spatial0 = (hh * 7) * HWIMG + ww * 7;
    const size_t nbase = (size_t)b * NPAD;

    // load q/k/v: per row i, 32 d = 4 x short8 chunks; comp 0/1/2 = q/k/v
    for (int idx = tid; idx < 49 * 4 * 3; idx += 256) {
        int comp = idx / 196;
        int rem = idx % 196;
        int i = rem >> 2, ds = (rem & 3) * 8;
        int n = spatial0 + (i / 7) * HWIMG + (i % 7);
        const unsigned short* src = qkv + (nbase + n) * QKV_M + comp * DIMC + head * HD + ds;
        short8 hv = *(const short8*)src;
        float* dst = (comp == 0) ? &q[i][ds] : (comp == 1) ? &k[i][ds] : &v[i][ds];
        #pragma unroll
        for (int t = 0; t < 8; ++t) dst[t] = bf2f((unsigned short)hv[t]);
    }
    __syncthreads();

    const float scale = 0.17677669529663687f;  // 32^-0.5
    for (int idx = tid; idx < 49 * 49; idx += 256) {
        int i = idx / 49, j = idx % 49;
        float s = 0.f;
        #pragma unroll
        for (int d = 0; d < HD; ++d) s += q[i][d] * k[j][d];
        dots[i][j] = s * scale + bias_table[rel_index[idx] * NH + head];
    }
    __syncthreads();

    if (tid < 49) {
        float m = -1e30f;
        for (int j = 0; j < 49; ++j) m = fmaxf(m, dots[tid][j]);
        float sum = 0.f;
        for (int j = 0; j < 49; ++j) { float e = __expf(dots[tid][j] - m); dots[tid][j] = e; sum += e; }
        float inv = 1.f / sum;
        for (int j = 0; j < 49; ++j) dots[tid][j] *= inv;
    }
    __syncthreads();

    for (int idx = tid; idx < 49 * 32; idx += 256) {
        int i = idx >> 5, d = idx & 31;
        float s = 0.f;
        #pragma unroll
        for (int j = 0; j < 49; ++j) s += dots[i][j] * v[j][d];
        int n = spatial0 + (i / 7) * HWIMG + (i % 7);
        outb[(nbase + n) * DIMC + head * HD + d] = f2bf(s);
    }
}

extern "C" void kernel_launch(void* const* d_in, const int* in_sizes, int n_in,
                              void* d_out, int out_size, void* d_ws, size_t ws_size,
                              hipStream_t stream) {
    const float* x          = (const float*)d_in[0];
    const float* w_qkv      = (const float*)d_in[1];
    const float* w_proj     = (const float*)d_in[2];
    const float* b_proj     = (const float*)d_in[3];
    const float* bias_table = (const float*)d_in[4];
    const int*   rel_index  = (const int*)d_in[5];

    unsigned short* xt   = (unsigned short*)d_ws;                 // [NTOT, 384]  78.6 MB
    unsigned short* qkvt = xt + (size_t)NTOT * KDIM;              // [NTOT, 1152] 235.9 MB
    unsigned short* att  = qkvt + (size_t)NTOT * QKV_M;           // [NTOT, 384]  78.6 MB
    unsigned short* wqb  = att + (size_t)NTOT * KDIM;             // [1152, 384]
    unsigned short* wpb  = wqb + QKV_M * KDIM;                    // [384, 384]

    cvt_w<<<(QKV_M * KDIM + 255) / 256, 256, 0, stream>>>(w_qkv, wqb, QKV_M * KDIM);
    cvt_w<<<(DIMC * KDIM + 255) / 256, 256, 0, stream>>>(w_proj, wpb, DIMC * KDIM);
    cvt_x<<<dim3(HW / 32, DIMC / 32, BATCH), 256, 0, stream>>>(x, xt);

    // GEMM1: qkv^T = (w_qkv @ x)^T, bf16 n-major
    gemm_mfma<0><<<dim3(NTOT / 128, QKV_M / 128), 256, 0, stream>>>(
        wqb, xt, nullptr, (void*)qkvt, QKV_M);

    // Attention per (window, head)
    win_attn<<<dim3(BATCH * 64 * NH), 256, 0, stream>>>(qkvt, bias_table, rel_index, att);

    // GEMM2: out = w_proj @ attn + b_proj, fp32 NCHW
    gemm_mfma<1><<<dim3(NTOT / 128, DIMC / 128), 256, 0, stream>>>(
        wpb, att, b_proj, d_out, 0);
}

// Round 3
// 424.447 us; speedup vs baseline: 5.6915x; 1.6913x over previous
//
#include <hip/hip_runtime.h>

#define NH 12
#define HD 32
#define DIMC 384
#define BATCH 32
#define HWIMG 56
#define NWIN 2048          // 32 batches * 64 windows
#define NROWS 100352       // NWIN * 49, dense window-gathered rows
#define QKV_M 1152
#define KDIM 384
#define QSCALE 0.17677669529663687f

typedef __attribute__((ext_vector_type(8))) short short8;
typedef __attribute__((ext_vector_type(4))) short short4v;
typedef __attribute__((ext_vector_type(4))) float f32x4;

typedef const __attribute__((address_space(1))) unsigned int* gas_ptr;
typedef __attribute__((address_space(3))) unsigned int* las_ptr;

__device__ __forceinline__ unsigned short f2bf(float f) {
    union { float f; unsigned u; } v; v.f = f;
    unsigned r = v.u + 0x7FFF + ((v.u >> 16) & 1);
    return (unsigned short)(r >> 16);
}

// ---------------- fp32 -> bf16 weight convert ----------------
__global__ __launch_bounds__(256) void cvt_w(const float* __restrict__ in,
                                             unsigned short* __restrict__ out, int n) {
    int i = blockIdx.x * 256 + threadIdx.x;
    if (i < n) out[i] = f2bf(in[i]);
}

// ---------------- x [B,384,56,56] fp32 -> xt [NROWS,384] bf16 (window-gathered) -------
__global__ __launch_bounds__(256) void cvt_x(const float* __restrict__ x,
                                             unsigned short* __restrict__ xt) {
    __shared__ float tile[32][33];
    const int b = blockIdx.z, c0 = blockIdx.y * 32, n0 = blockIdx.x * 32;
    const int tid = threadIdx.x;
    const int cl = tid >> 5, nl = tid & 31;
    #pragma unroll
    for (int p = 0; p < 4; ++p)
        tile[cl + p * 8][nl] = x[((size_t)b * DIMC + c0 + cl + p * 8) * 3136 + n0 + nl];
    __syncthreads();
    const int nl2 = tid >> 3, cq = (tid & 7) * 4;
    const int n = n0 + nl2;
    const int nh = n / HWIMG, nw = n % HWIMG;
    const int row = ((b * 64 + (nh / 7) * 8 + nw / 7) * 49 + (nh % 7) * 7 + nw % 7);
    short4v pk;
    #pragma unroll
    for (int u = 0; u < 4; ++u) pk[u] = (short)f2bf(tile[cq + u][nl2]);
    *(short4v*)(xt + (size_t)row * KDIM + c0 + cq) = pk;
}

// ---------------- bias expand: biasp[h][j:64][i:64] fp32, transposed & padded ----------
__global__ __launch_bounds__(256) void fill_bias(const float* __restrict__ bias_table,
                                                 const int* __restrict__ rel_index,
                                                 float* __restrict__ biasp) {
    int id = blockIdx.x * 256 + threadIdx.x;   // 12*4096
    int h = id >> 12, r = id & 4095;
    int j = r >> 6, i = r & 63;
    float v = 0.f;
    if (i < 49 && j < 49) v = bias_table[rel_index[i * 49 + j] * NH + h];
    biasp[id] = v;
}

// ---------------- zero the j-pad of vw ----------------
__global__ __launch_bounds__(256) void zero_vpad(unsigned short* __restrict__ vw) {
    int r = blockIdx.x * 256 + threadIdx.x;    // 2048*384 rows
    unsigned short* p = vw + (size_t)r * 64;
    p[49] = 0;
    unsigned* p4 = (unsigned*)(p + 50);
    #pragma unroll
    for (int u = 0; u < 7; ++u) p4[u] = 0;
}

// ---------------- bf16 MFMA GEMM over dense window rows ----------------
// C[m, ng] = sum_k A[m,k] * Bm[ng,k]
// MODE 0 (QKV): m<768 -> qkw[ng*768+m] bf16 (m<384 scaled by QSCALE);
//               m>=768 -> vw[(ng/49)*24576 + (m-768)*64 + ng%49] bf16
// MODE 1 (proj): fp32 NCHW + bias via window decode
template<int MODE>
__global__ __launch_bounds__(256) void gemm_mfma(
    const unsigned short* __restrict__ A,
    const unsigned short* __restrict__ Bm,
    const float* __restrict__ bias,
    void* __restrict__ Cout,
    unsigned short* __restrict__ Cv)
{
    __shared__ char Al[128 * 128];
    __shared__ char Bl[128 * 128];
    const int tid = threadIdx.x;
    // XCD-aware swizzle (grid.x*grid.y divisible by 8)
    const unsigned gx = gridDim.x;
    const unsigned nwg = gx * gridDim.y;
    const unsigned lin = blockIdx.y * gx + blockIdx.x;
    const unsigned swz = (lin & 7) * (nwg >> 3) + (lin >> 3);
    const int m0 = (swz / gx) * 128;
    const int ng0 = (swz % gx) * 128;

    const int lane = tid & 63;
    const int wv = tid >> 6;
    const int wr = wv >> 1, wc = wv & 1;
    const int lrow = lane & 15, kgrp = lane >> 4;

    f32x4 acc[4][4] = {};

    const char* Abase = (const char*)(A + (size_t)m0 * KDIM);
    const char* Bbase = (const char*)(Bm + (size_t)ng0 * KDIM);

    for (int kt = 0; kt < KDIM / 64; ++kt) {
        const int kb = kt * 128;
        #pragma unroll
        for (int it = 0; it < 4; ++it) {
            int chunk = it * 256 + tid;
            int row = chunk >> 3, slot = chunk & 7;
            int scol = (slot ^ (row & 7)) * 16;
            __builtin_amdgcn_global_load_lds(
                (gas_ptr)(Abase + (size_t)row * (KDIM * 2) + kb + scol),
                (las_ptr)(Al + chunk * 16), 16, 0, 0);
        }
        #pragma unroll
        for (int it = 0; it < 4; ++it) {
            int chunk = it * 256 + tid;
            int row = chunk >> 3, slot = chunk & 7;
            int scol = (slot ^ (row & 7)) * 16;
            __builtin_amdgcn_global_load_lds(
                (gas_ptr)(Bbase + (size_t)row * (KDIM * 2) + kb + scol),
                (las_ptr)(Bl + chunk * 16), 16, 0, 0);
        }
        __syncthreads();
        #pragma unroll
        for (int kk = 0; kk < 2; ++kk) {
            short8 af[4], bfr[4];
            #pragma unroll
            for (int i = 0; i < 4; ++i) {
                int row = wr * 64 + i * 16 + lrow;
                int slot = (kk * 4 + kgrp) ^ (row & 7);
                af[i] = *(const short8*)(Al + row * 128 + slot * 16);
            }
            #pragma unroll
            for (int j = 0; j < 4; ++j) {
                int row = wc * 64 + j * 16 + lrow;
                int slot = (kk * 4 + kgrp) ^ (row & 7);
                bfr[j] = *(const short8*)(Bl + row * 128 + slot * 16);
            }
            #pragma unroll
            for (int i = 0; i < 4; ++i)
                #pragma unroll
                for (int j = 0; j < 4; ++j)
                    acc[i][j] = __builtin_amdgcn_mfma_f32_16x16x32_bf16(af[i], bfr[j], acc[i][j], 0, 0, 0);
        }
        __syncthreads();
    }

    if (MODE == 0) {
        unsigned short* qk = (unsigned short*)Cout;
        const float sc = (m0 < 384) ? QSCALE : 1.0f;
        #pragma unroll
        for (int i = 0; i < 4; ++i) {
            int m = m0 + wr * 64 + i * 16 + kgrp * 4;
            #pragma unroll
            for (int j = 0; j < 4; ++j) {
                int ng = ng0 + wc * 64 + j * 16 + lrow;
                if (m < 768) {
                    short4v pk;
                    pk.x = (short)f2bf(acc[i][j].x * sc);
                    pk.y = (short)f2bf(acc[i][j].y * sc);
                    pk.z = (short)f2bf(acc[i][j].z * sc);
                    pk.w = (short)f2bf(acc[i][j].w * sc);
                    *(short4v*)(qk + (size_t)ng * 768 + m) = pk;
                } else {
                    unsigned win = (unsigned)ng / 49u;
                    unsigned ii = (unsigned)ng - win * 49u;
                    unsigned short* vb = Cv + (size_t)win * 24576 + (size_t)(m - 768) * 64 + ii;
                    vb[0]   = f2bf(acc[i][j].x);
                    vb[64]  = f2bf(acc[i][j].y);
                    vb[128] = f2bf(acc[i][j].z);
                    vb[192] = f2bf(acc[i][j].w);
                }
            }
        }
    } else {
        float* C = (float*)Cout;
        #pragma unroll
        for (int i = 0; i < 4; ++i) {
            int m = m0 + wr * 64 + i * 16 + kgrp * 4;
            float b0 = bias[m + 0], b1 = bias[m + 1], b2 = bias[m + 2], b3 = bias[m + 3];
            #pragma unroll
            for (int j = 0; j < 4; ++j) {
                int ng = ng0 + wc * 64 + j * 16 + lrow;
                unsigned win = (unsigned)ng / 49u;
                unsigned ii = (unsigned)ng - win * 49u;
                int b = win >> 6, wl = win & 63;
                int nsp = ((wl >> 3) * 7 + (int)ii / 7) * HWIMG + (wl & 7) * 7 + (int)ii % 7;
                C[((size_t)b * DIMC + m + 0) * 3136 + nsp] = acc[i][j].x + b0;
                C[((size_t)b * DIMC + m + 1) * 3136 + nsp] = acc[i][j].y + b1;
                C[((size_t)b * DIMC + m + 2) * 3136 + nsp] = acc[i][j].z + b2;
                C[((size_t)b * DIMC + m + 3) * 3136 + nsp] = acc[i][j].w + b3;
            }
        }
    }
}

// ---------------- MFMA windowed attention: one wave per (window, head), no LDS -------
__global__ __launch_bounds__(256) void win_attn(
    const unsigned short* __restrict__ qkw,   // [NROWS][768], q pre-scaled
    const unsigned short* __restrict__ vw,    // [NWIN][384][64]
    const float* __restrict__ biasp,          // [12][64][64]  (j-major, transposed)
    unsigned short* __restrict__ att)         // [NROWS][384]
{
    const int tid = threadIdx.x;
    const int lane = tid & 63;
    const int g = lane >> 4, c = lane & 15;
    const int bid = blockIdx.x;
    const int swz = (bid & 7) * 768 + (bid >> 3);       // 6144 blocks
    const int W = swz * 4 + (tid >> 6);
    const int win = W / 12;
    const int head = W - win * 12;

    const unsigned short* qbase = qkw + (size_t)win * 49 * 768 + head * HD;

    // K and Q fragments (identical addressing; K is A, Q is B)
    short8 kf[4], qf[4];
    #pragma unroll
    for (int a = 0; a < 4; ++a) {
        int r = a * 16 + c; if (r > 48) r = 48;
        kf[a] = *(const short8*)(qbase + (size_t)r * 768 + DIMC + g * 8);
        qf[a] = *(const short8*)(qbase + (size_t)r * 768 + g * 8);
    }

    // S^T fragments: s[a][bi], rows j = a*16+g*4+e, cols i = bi*16+c
    f32x4 s[4][4] = {};
    #pragma unroll
    for (int a = 0; a < 4; ++a)
        #pragma unroll
        for (int bi = 0; bi < 4; ++bi)
            s[a][bi] = __builtin_amdgcn_mfma_f32_16x16x32_bf16(kf[a], qf[bi], s[a][bi], 0, 0, 0);

    // bias + mask + per-column softmax (j-reduction: 16 in-lane + shfl 16,32)
    const float* bp = biasp + head * 4096;
    #pragma unroll
    for (int bi = 0; bi < 4; ++bi) {
        float mx = -1e30f;
        #pragma unroll
        for (int a = 0; a < 4; ++a) {
            #pragma unroll
            for (int e = 0; e < 4; ++e) {
                int j = a * 16 + g * 4 + e;
                float sv = s[a][bi][e] + bp[j * 64 + bi * 16 + c];
                sv = (j < 49) ? sv : -1e30f;
                s[a][bi][e] = sv;
                mx = fmaxf(mx, sv);
            }
        }
        mx = fmaxf(mx, __shfl_xor(mx, 16));
        mx = fmaxf(mx, __shfl_xor(mx, 32));
        float sum = 0.f;
        #pragma unroll
        for (int a = 0; a < 4; ++a) {
            #pragma unroll
            for (int e = 0; e < 4; ++e) {
                int j = a * 16 + g * 4 + e;
                float pv = (j < 49) ? __expf(s[a][bi][e] - mx) : 0.f;
                s[a][bi][e] = pv;
                sum += pv;
            }
        }
        sum += __shfl_xor(sum, 16);
        sum += __shfl_xor(sum, 32);
        float inv = 1.0f / sum;
        #pragma unroll
        for (int a = 0; a < 4; ++a)
            #pragma unroll
            for (int e = 0; e < 4; ++e)
                s[a][bi][e] *= inv;
    }

    // pack P' pairs along j: pk[a][bi][h] = bf16(P[j0]) | bf16(P[j0+1])<<16
    unsigned pk[4][4][2];
    #pragma unroll
    for (int a = 0; a < 4; ++a)
        #pragma unroll
        for (int bi = 0; bi < 4; ++bi)
            #pragma unroll
            for (int h = 0; h < 2; ++h)
                pk[a][bi][h] = (unsigned)f2bf(s[a][bi][2 * h]) |
                               ((unsigned)f2bf(s[a][bi][2 * h + 1]) << 16);

    // V fragments: direct from vw (d-major)
    const unsigned short* vbase = vw + (size_t)win * 24576 + head * HD * 64;
    short8 vf[2][2];
    #pragma unroll
    for (int tn = 0; tn < 2; ++tn)
        #pragma unroll
        for (int ks = 0; ks < 2; ++ks)
            vf[tn][ks] = *(const short8*)(vbase + (tn * 16 + c) * 64 + ks * 32 + g * 8);

    // PV: A = P^T via ds_bpermute repack, B = V
    f32x4 o[4][2] = {};
    const int gsel = g >> 1;
    const int sgb = 2 * (g & 1);
    #pragma unroll
    for (int ks = 0; ks < 2; ++ks) {
        #pragma unroll
        for (int to = 0; to < 4; ++to) {
            union { int w[4]; short8 v; } u;
            #pragma unroll
            for (int w = 0; w < 4; ++w) {
                int srcl = ((sgb + (w >> 1)) * 16 + c) << 2;
                int rA = __builtin_amdgcn_ds_bpermute(srcl, (int)pk[ks * 2 + 0][to][w & 1]);
                int rB = __builtin_amdgcn_ds_bpermute(srcl, (int)pk[ks * 2 + 1][to][w & 1]);
                u.w[w] = gsel ? rB : rA;
            }
            #pragma unroll
            for (int tn = 0; tn < 2; ++tn)
                o[to][tn] = __builtin_amdgcn_mfma_f32_16x16x32_bf16(u.v, vf[tn][ks], o[to][tn], 0, 0, 0);
        }
    }

    // store O rows i = to*16+g*4+e, cols d = tn*16+c
    unsigned short* ob = att + (size_t)win * 49 * DIMC + head * HD;
    #pragma unroll
    for (int to = 0; to < 4; ++to) {
        #pragma unroll
        for (int e = 0; e < 4; ++e) {
            int i = to * 16 + g * 4 + e;
            if (i < 49) {
                #pragma unroll
                for (int tn = 0; tn < 2; ++tn)
                    ob[(size_t)i * DIMC + tn * 16 + c] = f2bf(o[to][tn][e]);
            }
        }
    }
}

extern "C" void kernel_launch(void* const* d_in, const int* in_sizes, int n_in,
                              void* d_out, int out_size, void* d_ws, size_t ws_size,
                              hipStream_t stream) {
    const float* x          = (const float*)d_in[0];
    const float* w_qkv      = (const float*)d_in[1];
    const float* w_proj     = (const float*)d_in[2];
    const float* b_proj     = (const float*)d_in[3];
    const float* bias_table = (const float*)d_in[4];
    const int*   rel_index  = (const int*)d_in[5];

    // workspace layout (att aliases xt: xt consumed by GEMM1 before att is written)
    unsigned short* xt   = (unsigned short*)d_ws;                    // [NROWS][384]
    unsigned short* att  = xt;                                       // alias
    unsigned short* qkw  = xt + (size_t)NROWS * KDIM;                // [NROWS][768]
    unsigned short* vw   = qkw + (size_t)NROWS * 768;                // [NWIN][384][64]
    unsigned short* wqb  = vw + (size_t)NWIN * 384 * 64;             // [1152][384]
    unsigned short* wpb  = wqb + QKV_M * KDIM;                       // [384][384]
    float*          biasp = (float*)(wpb + DIMC * KDIM);             // [12][64][64]

    cvt_w<<<(QKV_M * KDIM + 255) / 256, 256, 0, stream>>>(w_qkv, wqb, QKV_M * KDIM);
    cvt_w<<<(DIMC * KDIM + 255) / 256, 256, 0, stream>>>(w_proj, wpb, DIMC * KDIM);
    cvt_x<<<dim3(98, 12, BATCH), 256, 0, stream>>>(x, xt);
    fill_bias<<<192, 256, 0, stream>>>(bias_table, rel_index, biasp);
    zero_vpad<<<3072, 256, 0, stream>>>(vw);

    // GEMM1: window-gathered qkw + vw
    gemm_mfma<0><<<dim3(NROWS / 128, QKV_M / 128), 256, 0, stream>>>(
        wqb, xt, nullptr, (void*)qkw, vw);

    // attention: 24576 (win,head) waves, 4 per block
    win_attn<<<6144, 256, 0, stream>>>(qkw, vw, biasp, att);

    // GEMM2: fp32 NCHW output + bias
    gemm_mfma<1><<<dim3(NROWS / 128, DIMC / 128), 256, 0, stream>>>(
        wpb, att, b_proj, d_out, nullptr);
}

// Round 4
// 405.430 us; speedup vs baseline: 5.9584x; 1.0469x over previous
//
#include <hip/hip_runtime.h>

#define NH 12
#define HD 32
#define DIMC 384
#define BATCH 32
#define HWIMG 56
#define NWIN 2048          // 32 batches * 64 windows
#define NROWS 100352       // NWIN * 49, dense window-gathered rows
#define QKV_M 1152
#define KDIM 384
#define QSCALE 0.17677669529663687f

typedef __attribute__((ext_vector_type(8))) short short8;
typedef __attribute__((ext_vector_type(4))) short short4v;
typedef __attribute__((ext_vector_type(4))) float f32x4;

typedef const __attribute__((address_space(1))) unsigned int* gas_ptr;
typedef __attribute__((address_space(3))) unsigned int* las_ptr;

__device__ __forceinline__ unsigned short f2bf(float f) {
    union { float f; unsigned u; } v; v.f = f;
    unsigned r = v.u + 0x7FFF + ((v.u >> 16) & 1);
    return (unsigned short)(r >> 16);
}

// ---------------- fp32 -> bf16 weight convert ----------------
__global__ __launch_bounds__(256) void cvt_w(const float* __restrict__ in,
                                             unsigned short* __restrict__ out, int n) {
    int i = blockIdx.x * 256 + threadIdx.x;
    if (i < n) out[i] = f2bf(in[i]);
}

// ---------------- x [B,384,56,56] fp32 -> xt [NROWS,384] bf16 (window-gathered) -------
__global__ __launch_bounds__(256) void cvt_x(const float* __restrict__ x,
                                             unsigned short* __restrict__ xt) {
    __shared__ float tile[32][33];
    const int b = blockIdx.z, c0 = blockIdx.y * 32, n0 = blockIdx.x * 32;
    const int tid = threadIdx.x;
    const int cl = tid >> 5, nl = tid & 31;
    #pragma unroll
    for (int p = 0; p < 4; ++p)
        tile[cl + p * 8][nl] = x[((size_t)b * DIMC + c0 + cl + p * 8) * 3136 + n0 + nl];
    __syncthreads();
    const int nl2 = tid >> 3, cq = (tid & 7) * 4;
    const int n = n0 + nl2;
    const int nh = n / HWIMG, nw = n % HWIMG;
    const int row = ((b * 64 + (nh / 7) * 8 + nw / 7) * 49 + (nh % 7) * 7 + nw % 7);
    short4v pk;
    #pragma unroll
    for (int u = 0; u < 4; ++u) pk[u] = (short)f2bf(tile[cq + u][nl2]);
    *(short4v*)(xt + (size_t)row * KDIM + c0 + cq) = pk;
}

// ---------------- bias expand: biasp[h][j:64][i:64] fp32, transposed & padded ----------
__global__ __launch_bounds__(256) void fill_bias(const float* __restrict__ bias_table,
                                                 const int* __restrict__ rel_index,
                                                 float* __restrict__ biasp) {
    int id = blockIdx.x * 256 + threadIdx.x;   // 12*4096
    int h = id >> 12, r = id & 4095;
    int j = r >> 6, i = r & 63;
    float v = 0.f;
    if (i < 49 && j < 49) v = bias_table[rel_index[i * 49 + j] * NH + h];
    biasp[id] = v;
}

// ---------------- zero the j-pad of vw ----------------
__global__ __launch_bounds__(256) void zero_vpad(unsigned short* __restrict__ vw) {
    int r = blockIdx.x * 256 + threadIdx.x;    // 2048*384 rows
    unsigned short* p = vw + (size_t)r * 64;
    p[49] = 0;
    unsigned* p4 = (unsigned*)(p + 50);
    #pragma unroll
    for (int u = 0; u < 7; ++u) p4[u] = 0;
}

// ---------------- bf16 MFMA GEMM over dense window rows ----------------
// C[m, ng] = sum_k A[m,k] * Bm[ng,k].  1-D grid, XCD-partitioned n-supertiles,
// m-fastest within each XCD chunk so B-tiles are L2-resident across all m.
// MODE 0 (QKV): m<768 -> qkw[ng*768+m] bf16 (m<384 scaled by QSCALE);
//               m>=768 -> vw[(ng/49)*24576 + (m-768)*64 + ng%49] bf16
// MODE 1 (proj): fp32 NCHW + bias; B rows are spatial-major (ng = b*3136+nsp)
template<int MODE>
__global__ __launch_bounds__(256) void gemm_mfma(
    const unsigned short* __restrict__ A,
    const unsigned short* __restrict__ Bm,
    const float* __restrict__ bias,
    void* __restrict__ Cout,
    unsigned short* __restrict__ Cv)
{
    __shared__ char Al[128 * 128];
    __shared__ char Bl[128 * 128];
    const int tid = threadIdx.x;

    constexpr int MT = (MODE == 0) ? 9 : 3;   // m-tiles
    const unsigned nwg = gridDim.x;
    const unsigned lin = blockIdx.x;
    const unsigned swz = (lin & 7) * (nwg >> 3) + (lin >> 3);  // XCD-contiguous
    const int m0 = (int)(swz % MT) * 128;
    const int ng0 = (int)(swz / MT) * 128;

    const int lane = tid & 63;
    const int wv = tid >> 6;
    const int wr = wv >> 1, wc = wv & 1;
    const int lrow = lane & 15, kgrp = lane >> 4;

    f32x4 acc[4][4] = {};

    const char* Abase = (const char*)(A + (size_t)m0 * KDIM);
    const char* Bbase = (const char*)(Bm + (size_t)ng0 * KDIM);

    for (int kt = 0; kt < KDIM / 64; ++kt) {
        const int kb = kt * 128;
        #pragma unroll
        for (int it = 0; it < 4; ++it) {
            int chunk = it * 256 + tid;
            int row = chunk >> 3, slot = chunk & 7;
            int scol = (slot ^ (row & 7)) * 16;
            __builtin_amdgcn_global_load_lds(
                (gas_ptr)(Abase + (size_t)row * (KDIM * 2) + kb + scol),
                (las_ptr)(Al + chunk * 16), 16, 0, 0);
        }
        #pragma unroll
        for (int it = 0; it < 4; ++it) {
            int chunk = it * 256 + tid;
            int row = chunk >> 3, slot = chunk & 7;
            int scol = (slot ^ (row & 7)) * 16;
            __builtin_amdgcn_global_load_lds(
                (gas_ptr)(Bbase + (size_t)row * (KDIM * 2) + kb + scol),
                (las_ptr)(Bl + chunk * 16), 16, 0, 0);
        }
        __syncthreads();
        #pragma unroll
        for (int kk = 0; kk < 2; ++kk) {
            short8 af[4], bfr[4];
            #pragma unroll
            for (int i = 0; i < 4; ++i) {
                int row = wr * 64 + i * 16 + lrow;
                int slot = (kk * 4 + kgrp) ^ (row & 7);
                af[i] = *(const short8*)(Al + row * 128 + slot * 16);
            }
            #pragma unroll
            for (int j = 0; j < 4; ++j) {
                int row = wc * 64 + j * 16 + lrow;
                int slot = (kk * 4 + kgrp) ^ (row & 7);
                bfr[j] = *(const short8*)(Bl + row * 128 + slot * 16);
            }
            #pragma unroll
            for (int i = 0; i < 4; ++i)
                #pragma unroll
                for (int j = 0; j < 4; ++j)
                    acc[i][j] = __builtin_amdgcn_mfma_f32_16x16x32_bf16(af[i], bfr[j], acc[i][j], 0, 0, 0);
        }
        __syncthreads();
    }

    if (MODE == 0) {
        unsigned short* qk = (unsigned short*)Cout;
        const float sc = (m0 < 384) ? QSCALE : 1.0f;
        #pragma unroll
        for (int i = 0; i < 4; ++i) {
            int m = m0 + wr * 64 + i * 16 + kgrp * 4;
            #pragma unroll
            for (int j = 0; j < 4; ++j) {
                int ng = ng0 + wc * 64 + j * 16 + lrow;
                if (m < 768) {
                    short4v pk;
                    pk.x = (short)f2bf(acc[i][j].x * sc);
                    pk.y = (short)f2bf(acc[i][j].y * sc);
                    pk.z = (short)f2bf(acc[i][j].z * sc);
                    pk.w = (short)f2bf(acc[i][j].w * sc);
                    *(short4v*)(qk + (size_t)ng * 768 + m) = pk;
                } else {
                    unsigned win = (unsigned)ng / 49u;
                    unsigned ii = (unsigned)ng - win * 49u;
                    unsigned short* vb = Cv + (size_t)win * 24576 + (size_t)(m - 768) * 64 + ii;
                    vb[0]   = f2bf(acc[i][j].x);
                    vb[64]  = f2bf(acc[i][j].y);
                    vb[128] = f2bf(acc[i][j].z);
                    vb[192] = f2bf(acc[i][j].w);
                }
            }
        }
    } else {
        float* C = (float*)Cout;
        #pragma unroll
        for (int i = 0; i < 4; ++i) {
            int m = m0 + wr * 64 + i * 16 + kgrp * 4;
            float b0 = bias[m + 0], b1 = bias[m + 1], b2 = bias[m + 2], b3 = bias[m + 3];
            #pragma unroll
            for (int j = 0; j < 4; ++j) {
                int ng = ng0 + wc * 64 + j * 16 + lrow;
                unsigned bb = (unsigned)ng / 3136u;
                unsigned nsp = (unsigned)ng - bb * 3136u;
                C[((size_t)bb * DIMC + m + 0) * 3136 + nsp] = acc[i][j].x + b0;
                C[((size_t)bb * DIMC + m + 1) * 3136 + nsp] = acc[i][j].y + b1;
                C[((size_t)bb * DIMC + m + 2) * 3136 + nsp] = acc[i][j].z + b2;
                C[((size_t)bb * DIMC + m + 3) * 3136 + nsp] = acc[i][j].w + b3;
            }
        }
    }
}

// ---------------- MFMA windowed attention: one wave per (window, head), no LDS -------
// Output att is SPATIAL-major: row = b*3136 + nsp  (so GEMM2 stores coalesce)
__global__ __launch_bounds__(256) void win_attn(
    const unsigned short* __restrict__ qkw,   // [NROWS][768], q pre-scaled, win-major
    const unsigned short* __restrict__ vw,    // [NWIN][384][64]
    const float* __restrict__ biasp,          // [12][64][64]  (j-major, transposed)
    unsigned short* __restrict__ att)         // [B*3136][384] spatial-major
{
    const int tid = threadIdx.x;
    const int lane = tid & 63;
    const int g = lane >> 4, c = lane & 15;
    const int bid = blockIdx.x;
    const int swz = (bid & 7) * 768 + (bid >> 3);       // 6144 blocks
    const int W = swz * 4 + (tid >> 6);
    const int win = W / 12;
    const int head = W - win * 12;

    const unsigned short* qbase = qkw + (size_t)win * 49 * 768 + head * HD;

    short8 kf[4], qf[4];
    #pragma unroll
    for (int a = 0; a < 4; ++a) {
        int r = a * 16 + c; if (r > 48) r = 48;
        kf[a] = *(const short8*)(qbase + (size_t)r * 768 + DIMC + g * 8);
        qf[a] = *(const short8*)(qbase + (size_t)r * 768 + g * 8);
    }

    // S^T fragments: rows j = a*16+g*4+e, cols i = bi*16+c
    f32x4 s[4][4] = {};
    #pragma unroll
    for (int a = 0; a < 4; ++a)
        #pragma unroll
        for (int bi = 0; bi < 4; ++bi)
            s[a][bi] = __builtin_amdgcn_mfma_f32_16x16x32_bf16(kf[a], qf[bi], s[a][bi], 0, 0, 0);

    const float* bp = biasp + head * 4096;
    #pragma unroll
    for (int bi = 0; bi < 4; ++bi) {
        float mx = -1e30f;
        #pragma unroll
        for (int a = 0; a < 4; ++a) {
            #pragma unroll
            for (int e = 0; e < 4; ++e) {
                int j = a * 16 + g * 4 + e;
                float sv = s[a][bi][e] + bp[j * 64 + bi * 16 + c];
                sv = (j < 49) ? sv : -1e30f;
                s[a][bi][e] = sv;
                mx = fmaxf(mx, sv);
            }
        }
        mx = fmaxf(mx, __shfl_xor(mx, 16));
        mx = fmaxf(mx, __shfl_xor(mx, 32));
        float sum = 0.f;
        #pragma unroll
        for (int a = 0; a < 4; ++a) {
            #pragma unroll
            for (int e = 0; e < 4; ++e) {
                int j = a * 16 + g * 4 + e;
                float pv = (j < 49) ? __expf(s[a][bi][e] - mx) : 0.f;
                s[a][bi][e] = pv;
                sum += pv;
            }
        }
        sum += __shfl_xor(sum, 16);
        sum += __shfl_xor(sum, 32);
        float inv = 1.0f / sum;
        #pragma unroll
        for (int a = 0; a < 4; ++a)
            #pragma unroll
            for (int e = 0; e < 4; ++e)
                s[a][bi][e] *= inv;
    }

    unsigned pk[4][4][2];
    #pragma unroll
    for (int a = 0; a < 4; ++a)
        #pragma unroll
        for (int bi = 0; bi < 4; ++bi)
            #pragma unroll
            for (int h = 0; h < 2; ++h)
                pk[a][bi][h] = (unsigned)f2bf(s[a][bi][2 * h]) |
                               ((unsigned)f2bf(s[a][bi][2 * h + 1]) << 16);

    const unsigned short* vbase = vw + (size_t)win * 24576 + head * HD * 64;
    short8 vf[2][2];
    #pragma unroll
    for (int tn = 0; tn < 2; ++tn)
        #pragma unroll
        for (int ks = 0; ks < 2; ++ks)
            vf[tn][ks] = *(const short8*)(vbase + (tn * 16 + c) * 64 + ks * 32 + g * 8);

    f32x4 o[4][2] = {};
    const int gsel = g >> 1;
    const int sgb = 2 * (g & 1);
    #pragma unroll
    for (int ks = 0; ks < 2; ++ks) {
        #pragma unroll
        for (int to = 0; to < 4; ++to) {
            union { int w[4]; short8 v; } u;
            #pragma unroll
            for (int w = 0; w < 4; ++w) {
                int srcl = ((sgb + (w >> 1)) * 16 + c) << 2;
                int rA = __builtin_amdgcn_ds_bpermute(srcl, (int)pk[ks * 2 + 0][to][w & 1]);
                int rB = __builtin_amdgcn_ds_bpermute(srcl, (int)pk[ks * 2 + 1][to][w & 1]);
                u.w[w] = gsel ? rB : rA;
            }
            #pragma unroll
            for (int tn = 0; tn < 2; ++tn)
                o[to][tn] = __builtin_amdgcn_mfma_f32_16x16x32_bf16(u.v, vf[tn][ks], o[to][tn], 0, 0, 0);
        }
    }

    // store O rows i = to*16+g*4+e (i<49), cols d = tn*16+c, to spatial-major att
    const int wl = win & 63, bb = win >> 6;
    const size_t obase = (size_t)bb * 3136 * DIMC;
    const int nsp0 = (wl >> 3) * 7 * HWIMG + (wl & 7) * 7;
    #pragma unroll
    for (int to = 0; to < 4; ++to) {
        #pragma unroll
        for (int e = 0; e < 4; ++e) {
            int i = to * 16 + g * 4 + e;
            if (i < 49) {
                int nsp = nsp0 + (i / 7) * HWIMG + (i % 7);
                unsigned short* ob = att + obase + (size_t)nsp * DIMC + head * HD;
                #pragma unroll
                for (int tn = 0; tn < 2; ++tn)
                    ob[tn * 16 + c] = f2bf(o[to][tn][e]);
            }
        }
    }
}

extern "C" void kernel_launch(void* const* d_in, const int* in_sizes, int n_in,
                              void* d_out, int out_size, void* d_ws, size_t ws_size,
                              hipStream_t stream) {
    const float* x          = (const float*)d_in[0];
    const float* w_qkv      = (const float*)d_in[1];
    const float* w_proj     = (const float*)d_in[2];
    const float* b_proj     = (const float*)d_in[3];
    const float* bias_table = (const float*)d_in[4];
    const int*   rel_index  = (const int*)d_in[5];

    // workspace layout (att aliases xt: xt consumed by GEMM1 before att is written)
    unsigned short* xt   = (unsigned short*)d_ws;                    // [NROWS][384]
    unsigned short* att  = xt;                                       // alias, spatial-major
    unsigned short* qkw  = xt + (size_t)NROWS * KDIM;                // [NROWS][768]
    unsigned short* vw   = qkw + (size_t)NROWS * 768;                // [NWIN][384][64]
    unsigned short* wqb  = vw + (size_t)NWIN * 384 * 64;             // [1152][384]
    unsigned short* wpb  = wqb + QKV_M * KDIM;                       // [384][384]
    float*          biasp = (float*)(wpb + DIMC * KDIM);             // [12][64][64]

    cvt_w<<<(QKV_M * KDIM + 255) / 256, 256, 0, stream>>>(w_qkv, wqb, QKV_M * KDIM);
    cvt_w<<<(DIMC * KDIM + 255) / 256, 256, 0, stream>>>(w_proj, wpb, DIMC * KDIM);
    cvt_x<<<dim3(98, 12, BATCH), 256, 0, stream>>>(x, xt);
    fill_bias<<<192, 256, 0, stream>>>(bias_table, rel_index, biasp);
    zero_vpad<<<3072, 256, 0, stream>>>(vw);

    // GEMM1: 9 m-tiles x 784 n-tiles = 7056 blocks (1-D, XCD-supertiled)
    gemm_mfma<0><<<7056, 256, 0, stream>>>(wqb, xt, nullptr, (void*)qkw, vw);

    // attention: 24576 (win,head) waves, 4 per block
    win_attn<<<6144, 256, 0, stream>>>(qkw, vw, biasp, att);

    // GEMM2: 3 m-tiles x 784 n-tiles = 2352 blocks; spatial-major B, coalesced NCHW out
    gemm_mfma<1><<<2352, 256, 0, stream>>>(wpb, att, b_proj, d_out, nullptr);
}

// Round 5
// 403.200 us; speedup vs baseline: 5.9914x; 1.0055x over previous
//
#include <hip/hip_runtime.h>

#define NH 12
#define HD 32
#define DIMC 384
#define BATCH 32
#define HWIMG 56
#define NWIN 2048          // 32 batches * 64 windows
#define NROWS 100352       // NWIN * 49, dense window-gathered rows
#define QKV_M 1152
#define KDIM 384
#define QSCALE 0.17677669529663687f

typedef __attribute__((ext_vector_type(8))) short short8;
typedef __attribute__((ext_vector_type(4))) short short4v;
typedef __attribute__((ext_vector_type(4))) float f32x4;

typedef const __attribute__((address_space(1))) unsigned int* gas_ptr;
typedef __attribute__((address_space(3))) unsigned int* las_ptr;

__device__ __forceinline__ unsigned short f2bf(float f) {
    union { float f; unsigned u; } v; v.f = f;
    unsigned r = v.u + 0x7FFF + ((v.u >> 16) & 1);
    return (unsigned short)(r >> 16);
}

// ---------------- fp32 -> bf16 weight convert ----------------
__global__ __launch_bounds__(256) void cvt_w(const float* __restrict__ in,
                                             unsigned short* __restrict__ out, int n) {
    int i = blockIdx.x * 256 + threadIdx.x;
    if (i < n) out[i] = f2bf(in[i]);
}

// ---------------- x [B,384,56,56] fp32 -> xt [NROWS,384] bf16 (window-gathered) -------
__global__ __launch_bounds__(256) void cvt_x(const float* __restrict__ x,
                                             unsigned short* __restrict__ xt) {
    __shared__ float tile[32][33];
    const int b = blockIdx.z, c0 = blockIdx.y * 32, n0 = blockIdx.x * 32;
    const int tid = threadIdx.x;
    const int cl = tid >> 5, nl = tid & 31;
    #pragma unroll
    for (int p = 0; p < 4; ++p)
        tile[cl + p * 8][nl] = x[((size_t)b * DIMC + c0 + cl + p * 8) * 3136 + n0 + nl];
    __syncthreads();
    const int nl2 = tid >> 3, cq = (tid & 7) * 4;
    const int n = n0 + nl2;
    const int nh = n / HWIMG, nw = n % HWIMG;
    const int row = ((b * 64 + (nh / 7) * 8 + nw / 7) * 49 + (nh % 7) * 7 + nw % 7);
    short4v pk;
    #pragma unroll
    for (int u = 0; u < 4; ++u) pk[u] = (short)f2bf(tile[cq + u][nl2]);
    *(short4v*)(xt + (size_t)row * KDIM + c0 + cq) = pk;
}

// ---------------- bias expand: biasp[h][j:64][i:64] fp32, transposed & padded ----------
__global__ __launch_bounds__(256) void fill_bias(const float* __restrict__ bias_table,
                                                 const int* __restrict__ rel_index,
                                                 float* __restrict__ biasp) {
    int id = blockIdx.x * 256 + threadIdx.x;   // 12*4096
    int h = id >> 12, r = id & 4095;
    int j = r >> 6, i = r & 63;
    float v = 0.f;
    if (i < 49 && j < 49) v = bias_table[rel_index[i * 49 + j] * NH + h];
    biasp[id] = v;
}

// ---------------- zero the j-pad of vw ----------------
__global__ __launch_bounds__(256) void zero_vpad(unsigned short* __restrict__ vw) {
    int r = blockIdx.x * 256 + threadIdx.x;    // 2048*384 rows
    unsigned short* p = vw + (size_t)r * 64;
    p[49] = 0;
    unsigned* p4 = (unsigned*)(p + 50);
    #pragma unroll
    for (int u = 0; u < 7; ++u) p4[u] = 0;
}

// ---------------- bf16 MFMA GEMM, 2-phase double-buffered K-loop ----------------
// C[m, ng] = sum_k A[m,k] * Bm[ng,k].  1-D grid, XCD-partitioned n-supertiles,
// m-fastest within each XCD chunk so B-tiles are L2-resident across all m.
// Per K-step: one __syncthreads (implicit vmcnt(0) drains PREVIOUS prefetch),
// then issue next-tile global_load_lds, then compute current buffer.
// MODE 0 (QKV): m<768 -> qkw[ng*768+m] bf16 (m<384 scaled by QSCALE);
//               m>=768 -> vw[(ng/49)*24576 + (m-768)*64 + ng%49] bf16
// MODE 1 (proj): fp32 NCHW + bias; B rows are spatial-major (ng = b*3136+nsp)
template<int MODE>
__global__ __launch_bounds__(256) void gemm_mfma(
    const unsigned short* __restrict__ A,
    const unsigned short* __restrict__ Bm,
    const float* __restrict__ bias,
    void* __restrict__ Cout,
    unsigned short* __restrict__ Cv)
{
    __shared__ char L[2][32768];   // [buf][A 16KB | B 16KB], XOR-swizzled 16B slots
    const int tid = threadIdx.x;

    constexpr int MT = (MODE == 0) ? 9 : 3;   // m-tiles
    const unsigned nwg = gridDim.x;
    const unsigned lin = blockIdx.x;
    const unsigned swz = (lin & 7) * (nwg >> 3) + (lin >> 3);  // XCD-contiguous
    const int m0 = (int)(swz % MT) * 128;
    const int ng0 = (int)(swz / MT) * 128;

    const int lane = tid & 63;
    const int wv = tid >> 6;
    const int wr = wv >> 1, wc = wv & 1;
    const int lrow = lane & 15, kgrp = lane >> 4;

    f32x4 acc[4][4] = {};

    const char* Abase = (const char*)(A + (size_t)m0 * KDIM);
    const char* Bbase = (const char*)(Bm + (size_t)ng0 * KDIM);

    // staging: 128 rows x 128 B per operand; 8 chunks of 16 B per thread total
    const int s_row = tid >> 3, s_slot = tid & 7;
    const int s_scol = (s_slot ^ (s_row & 7)) * 16;

    auto stage = [&](int kt, int bufi) {
        const int kb = kt * 128;
        #pragma unroll
        for (int it = 0; it < 4; ++it) {
            int chunk = it * 256 + tid;
            int row = chunk >> 3, slot = chunk & 7;
            int scol = (slot ^ (row & 7)) * 16;
            __builtin_amdgcn_global_load_lds(
                (gas_ptr)(Abase + (size_t)row * (KDIM * 2) + kb + scol),
                (las_ptr)(L[bufi] + chunk * 16), 16, 0, 0);
        }
        #pragma unroll
        for (int it = 0; it < 4; ++it) {
            int chunk = it * 256 + tid;
            int row = chunk >> 3, slot = chunk & 7;
            int scol = (slot ^ (row & 7)) * 16;
            __builtin_amdgcn_global_load_lds(
                (gas_ptr)(Bbase + (size_t)row * (KDIM * 2) + kb + scol),
                (las_ptr)(L[bufi] + 16384 + chunk * 16), 16, 0, 0);
        }
    };

    stage(0, 0);

    #pragma unroll
    for (int kt = 0; kt < KDIM / 64; ++kt) {
        __syncthreads();   // implicit vmcnt(0): buffer (kt&1) is ready
        if (kt + 1 < KDIM / 64) stage(kt + 1, (kt + 1) & 1);   // prefetch under compute
        const char* Al = L[kt & 1];
        const char* Bl = L[kt & 1] + 16384;
        #pragma unroll
        for (int kk = 0; kk < 2; ++kk) {
            short8 af[4], bfr[4];
            #pragma unroll
            for (int i = 0; i < 4; ++i) {
                int row = wr * 64 + i * 16 + lrow;
                int slot = (kk * 4 + kgrp) ^ (row & 7);
                af[i] = *(const short8*)(Al + row * 128 + slot * 16);
            }
            #pragma unroll
            for (int j = 0; j < 4; ++j) {
                int row = wc * 64 + j * 16 + lrow;
                int slot = (kk * 4 + kgrp) ^ (row & 7);
                bfr[j] = *(const short8*)(Bl + row * 128 + slot * 16);
            }
            __builtin_amdgcn_s_setprio(1);
            #pragma unroll
            for (int i = 0; i < 4; ++i)
                #pragma unroll
                for (int j = 0; j < 4; ++j)
                    acc[i][j] = __builtin_amdgcn_mfma_f32_16x16x32_bf16(af[i], bfr[j], acc[i][j], 0, 0, 0);
            __builtin_amdgcn_s_setprio(0);
        }
    }

    if (MODE == 0) {
        unsigned short* qk = (unsigned short*)Cout;
        const float sc = (m0 < 384) ? QSCALE : 1.0f;
        #pragma unroll
        for (int i = 0; i < 4; ++i) {
            int m = m0 + wr * 64 + i * 16 + kgrp * 4;
            #pragma unroll
            for (int j = 0; j < 4; ++j) {
                int ng = ng0 + wc * 64 + j * 16 + lrow;
                if (m < 768) {
                    short4v pk;
                    pk.x = (short)f2bf(acc[i][j].x * sc);
                    pk.y = (short)f2bf(acc[i][j].y * sc);
                    pk.z = (short)f2bf(acc[i][j].z * sc);
                    pk.w = (short)f2bf(acc[i][j].w * sc);
                    *(short4v*)(qk + (size_t)ng * 768 + m) = pk;
                } else {
                    unsigned win = (unsigned)ng / 49u;
                    unsigned ii = (unsigned)ng - win * 49u;
                    unsigned short* vb = Cv + (size_t)win * 24576 + (size_t)(m - 768) * 64 + ii;
                    vb[0]   = f2bf(acc[i][j].x);
                    vb[64]  = f2bf(acc[i][j].y);
                    vb[128] = f2bf(acc[i][j].z);
                    vb[192] = f2bf(acc[i][j].w);
                }
            }
        }
    } else {
        float* C = (float*)Cout;
        #pragma unroll
        for (int i = 0; i < 4; ++i) {
            int m = m0 + wr * 64 + i * 16 + kgrp * 4;
            float b0 = bias[m + 0], b1 = bias[m + 1], b2 = bias[m + 2], b3 = bias[m + 3];
            #pragma unroll
            for (int j = 0; j < 4; ++j) {
                int ng = ng0 + wc * 64 + j * 16 + lrow;
                unsigned bb = (unsigned)ng / 3136u;
                unsigned nsp = (unsigned)ng - bb * 3136u;
                C[((size_t)bb * DIMC + m + 0) * 3136 + nsp] = acc[i][j].x + b0;
                C[((size_t)bb * DIMC + m + 1) * 3136 + nsp] = acc[i][j].y + b1;
                C[((size_t)bb * DIMC + m + 2) * 3136 + nsp] = acc[i][j].z + b2;
                C[((size_t)bb * DIMC + m + 3) * 3136 + nsp] = acc[i][j].w + b3;
            }
        }
    }
}

// ---------------- MFMA windowed attention: one wave per (window, head), no LDS -------
// Output att is SPATIAL-major: row = b*3136 + nsp  (so GEMM2 stores coalesce)
__global__ __launch_bounds__(256) void win_attn(
    const unsigned short* __restrict__ qkw,   // [NROWS][768], q pre-scaled, win-major
    const unsigned short* __restrict__ vw,    // [NWIN][384][64]
    const float* __restrict__ biasp,          // [12][64][64]  (j-major, transposed)
    unsigned short* __restrict__ att)         // [B*3136][384] spatial-major
{
    const int tid = threadIdx.x;
    const int lane = tid & 63;
    const int g = lane >> 4, c = lane & 15;
    const int bid = blockIdx.x;
    const int swz = (bid & 7) * 768 + (bid >> 3);       // 6144 blocks
    const int W = swz * 4 + (tid >> 6);
    const int win = W / 12;
    const int head = W - win * 12;

    const unsigned short* qbase = qkw + (size_t)win * 49 * 768 + head * HD;

    short8 kf[4], qf[4];
    #pragma unroll
    for (int a = 0; a < 4; ++a) {
        int r = a * 16 + c; if (r > 48) r = 48;
        kf[a] = *(const short8*)(qbase + (size_t)r * 768 + DIMC + g * 8);
        qf[a] = *(const short8*)(qbase + (size_t)r * 768 + g * 8);
    }

    // S^T fragments: rows j = a*16+g*4+e, cols i = bi*16+c
    f32x4 s[4][4] = {};
    #pragma unroll
    for (int a = 0; a < 4; ++a)
        #pragma unroll
        for (int bi = 0; bi < 4; ++bi)
            s[a][bi] = __builtin_amdgcn_mfma_f32_16x16x32_bf16(kf[a], qf[bi], s[a][bi], 0, 0, 0);

    const float* bp = biasp + head * 4096;
    #pragma unroll
    for (int bi = 0; bi < 4; ++bi) {
        float mx = -1e30f;
        #pragma unroll
        for (int a = 0; a < 4; ++a) {
            #pragma unroll
            for (int e = 0; e < 4; ++e) {
                int j = a * 16 + g * 4 + e;
                float sv = s[a][bi][e] + bp[j * 64 + bi * 16 + c];
                sv = (j < 49) ? sv : -1e30f;
                s[a][bi][e] = sv;
                mx = fmaxf(mx, sv);
            }
        }
        mx = fmaxf(mx, __shfl_xor(mx, 16));
        mx = fmaxf(mx, __shfl_xor(mx, 32));
        float sum = 0.f;
        #pragma unroll
        for (int a = 0; a < 4; ++a) {
            #pragma unroll
            for (int e = 0; e < 4; ++e) {
                int j = a * 16 + g * 4 + e;
                float pv = (j < 49) ? __expf(s[a][bi][e] - mx) : 0.f;
                s[a][bi][e] = pv;
                sum += pv;
            }
        }
        sum += __shfl_xor(sum, 16);
        sum += __shfl_xor(sum, 32);
        float inv = 1.0f / sum;
        #pragma unroll
        for (int a = 0; a < 4; ++a)
            #pragma unroll
            for (int e = 0; e < 4; ++e)
                s[a][bi][e] *= inv;
    }

    unsigned pk[4][4][2];
    #pragma unroll
    for (int a = 0; a < 4; ++a)
        #pragma unroll
        for (int bi = 0; bi < 4; ++bi)
            #pragma unroll
            for (int h = 0; h < 2; ++h)
                pk[a][bi][h] = (unsigned)f2bf(s[a][bi][2 * h]) |
                               ((unsigned)f2bf(s[a][bi][2 * h + 1]) << 16);

    const unsigned short* vbase = vw + (size_t)win * 24576 + head * HD * 64;
    short8 vf[2][2];
    #pragma unroll
    for (int tn = 0; tn < 2; ++tn)
        #pragma unroll
        for (int ks = 0; ks < 2; ++ks)
            vf[tn][ks] = *(const short8*)(vbase + (tn * 16 + c) * 64 + ks * 32 + g * 8);

    f32x4 o[4][2] = {};
    const int gsel = g >> 1;
    const int sgb = 2 * (g & 1);
    #pragma unroll
    for (int ks = 0; ks < 2; ++ks) {
        #pragma unroll
        for (int to = 0; to < 4; ++to) {
            union { int w[4]; short8 v; } u;
            #pragma unroll
            for (int w = 0; w < 4; ++w) {
                int srcl = ((sgb + (w >> 1)) * 16 + c) << 2;
                int rA = __builtin_amdgcn_ds_bpermute(srcl, (int)pk[ks * 2 + 0][to][w & 1]);
                int rB = __builtin_amdgcn_ds_bpermute(srcl, (int)pk[ks * 2 + 1][to][w & 1]);
                u.w[w] = gsel ? rB : rA;
            }
            #pragma unroll
            for (int tn = 0; tn < 2; ++tn)
                o[to][tn] = __builtin_amdgcn_mfma_f32_16x16x32_bf16(u.v, vf[tn][ks], o[to][tn], 0, 0, 0);
        }
    }

    // store O rows i = to*16+g*4+e (i<49), cols d = tn*16+c, to spatial-major att
    const int wl = win & 63, bb = win >> 6;
    const size_t obase = (size_t)bb * 3136 * DIMC;
    const int nsp0 = (wl >> 3) * 7 * HWIMG + (wl & 7) * 7;
    #pragma unroll
    for (int to = 0; to < 4; ++to) {
        #pragma unroll
        for (int e = 0; e < 4; ++e) {
            int i = to * 16 + g * 4 + e;
            if (i < 49) {
                int nsp = nsp0 + (i / 7) * HWIMG + (i % 7);
                unsigned short* ob = att + obase + (size_t)nsp * DIMC + head * HD;
                #pragma unroll
                for (int tn = 0; tn < 2; ++tn)
                    ob[tn * 16 + c] = f2bf(o[to][tn][e]);
            }
        }
    }
}

extern "C" void kernel_launch(void* const* d_in, const int* in_sizes, int n_in,
                              void* d_out, int out_size, void* d_ws, size_t ws_size,
                              hipStream_t stream) {
    const float* x          = (const float*)d_in[0];
    const float* w_qkv      = (const float*)d_in[1];
    const float* w_proj     = (const float*)d_in[2];
    const float* b_proj     = (const float*)d_in[3];
    const float* bias_table = (const float*)d_in[4];
    const int*   rel_index  = (const int*)d_in[5];

    // workspace layout (att aliases xt: xt consumed by GEMM1 before att is written)
    unsigned short* xt   = (unsigned short*)d_ws;                    // [NROWS][384]
    unsigned short* att  = xt;                                       // alias, spatial-major
    unsigned short* qkw  = xt + (size_t)NROWS * KDIM;                // [NROWS][768]
    unsigned short* vw   = qkw + (size_t)NROWS * 768;                // [NWIN][384][64]
    unsigned short* wqb  = vw + (size_t)NWIN * 384 * 64;             // [1152][384]
    unsigned short* wpb  = wqb + QKV_M * KDIM;                       // [384][384]
    float*          biasp = (float*)(wpb + DIMC * KDIM);             // [12][64][64]

    cvt_w<<<(QKV_M * KDIM + 255) / 256, 256, 0, stream>>>(w_qkv, wqb, QKV_M * KDIM);
    cvt_w<<<(DIMC * KDIM + 255) / 256, 256, 0, stream>>>(w_proj, wpb, DIMC * KDIM);
    cvt_x<<<dim3(98, 12, BATCH), 256, 0, stream>>>(x, xt);
    fill_bias<<<192, 256, 0, stream>>>(bias_table, rel_index, biasp);
    zero_vpad<<<3072, 256, 0, stream>>>(vw);

    // GEMM1: 9 m-tiles x 784 n-tiles = 7056 blocks (1-D, XCD-supertiled)
    gemm_mfma<0><<<7056, 256, 0, stream>>>(wqb, xt, nullptr, (void*)qkw, vw);

    // attention: 24576 (win,head) waves, 4 per block
    win_attn<<<6144, 256, 0, stream>>>(qkw, vw, biasp, att);

    // GEMM2: 3 m-tiles x 784 n-tiles = 2352 blocks; spatial-major B, coalesced NCHW out
    gemm_mfma<1><<<2352, 256, 0, stream>>>(wpb, att, b_proj, d_out, nullptr);
}